// Round 8
// baseline (453.340 us; speedup 1.0000x reference)
//
#include <hip/hip_runtime.h>
#include <math.h>

#define D_DIM 128
#define H_DIM 128
#define SQRT_H_INV 0.08838834764831845f
// packed B panel columns: [wq 512 | wk 512 | wv 512 | wskip 128 | g0 512 | g1 512 | wih-igo 384]
#define BCOL_QKV 0
#define BCOL_G0 1664
#define BCOL_G1 2176
#define BCOL_W  2688
#define BCOL_TOT 3072

typedef unsigned short u16;
typedef unsigned short ushort8v __attribute__((ext_vector_type(8)));
typedef __bf16 bf16x8 __attribute__((ext_vector_type(8)));
typedef float f32x4 __attribute__((ext_vector_type(4)));

__device__ __forceinline__ float grp16_sum(float v) {
  v += __shfl_xor(v, 1);
  v += __shfl_xor(v, 2);
  v += __shfl_xor(v, 4);
  v += __shfl_xor(v, 8);
  return v;
}

__device__ __forceinline__ void split_bf16(float x, u16& h, u16& l) {
  __bf16 hb = (__bf16)x;
  float rm = x - (float)hb;
  __bf16 lb = (__bf16)rm;
  h = __builtin_bit_cast(u16, hb);
  l = __builtin_bit_cast(u16, lb);
}

// ---------------------------------------------------------------------------
__global__ __launch_bounds__(128) void k_event(
    const float* __restrict__ ef, int EV,
    const float* __restrict__ w1, const float* __restrict__ b1,
    const float* __restrict__ g1, const float* __restrict__ bt1,
    const float* __restrict__ w2, const float* __restrict__ b2,
    const float* __restrict__ g2, const float* __restrict__ bt2,
    const float* __restrict__ ett, const int* __restrict__ etid,
    const float* __restrict__ inten, int K,
    float* __restrict__ e_out)
{
  __shared__ float sh[H_DIM];
  __shared__ float red[H_DIM];
  const int t = threadIdx.x;

  float acc = b1[t];
  for (int i = 0; i < EV; ++i) acc += ef[i] * w1[i * H_DIM + t];

  red[t] = acc; __syncthreads();
  for (int s = 64; s > 0; s >>= 1) { if (t < s) red[t] += red[t + s]; __syncthreads(); }
  float mu = red[0] / H_DIM; __syncthreads();
  float d = acc - mu;
  red[t] = d * d; __syncthreads();
  for (int s = 64; s > 0; s >>= 1) { if (t < s) red[t] += red[t + s]; __syncthreads(); }
  float var = red[0] / H_DIM; __syncthreads();
  float y = d * rsqrtf(var + 1e-5f) * g1[t] + bt1[t];
  y = fmaxf(y, 0.f);
  sh[t] = y; __syncthreads();

  float acc2 = b2[t];
  for (int i = 0; i < H_DIM; ++i) acc2 += sh[i] * w2[i * H_DIM + t];

  red[t] = acc2; __syncthreads();
  for (int s = 64; s > 0; s >>= 1) { if (t < s) red[t] += red[t + s]; __syncthreads(); }
  mu = red[0] / H_DIM; __syncthreads();
  d = acc2 - mu;
  red[t] = d * d; __syncthreads();
  for (int s = 64; s > 0; s >>= 1) { if (t < s) red[t] += red[t + s]; __syncthreads(); }
  var = red[0] / H_DIM; __syncthreads();
  float y2 = d * rsqrtf(var + 1e-5f) * g2[t] + bt2[t];
  y2 = fmaxf(y2, 0.f);

  float m = 0.f;
  for (int k = 0; k < K; ++k) m += ett[etid[k] * H_DIM + t] * inten[k];
  e_out[t] = y2 + m / (float)K;
}

// ---------------------------------------------------------------------------
// cvec1[1664] = e @ W[128:256] + b for q|k|v|skip ; cvec2[384] = (bih+bhh)
// permuted to (i,g,o) gate order.
// ---------------------------------------------------------------------------
__global__ __launch_bounds__(256) void k_cvec_all(
    const float* __restrict__ e,
    const float* __restrict__ wq, const float* __restrict__ bq,
    const float* __restrict__ wk, const float* __restrict__ bk,
    const float* __restrict__ wv, const float* __restrict__ bv,
    const float* __restrict__ wskip, const float* __restrict__ bskip,
    const float* __restrict__ bih, const float* __restrict__ bhh,
    float* __restrict__ cvec1, float* __restrict__ cvec2)
{
  __shared__ float es[H_DIM];
  const int t = threadIdx.x;
  if (t < H_DIM) es[t] = e[t];
  __syncthreads();
  int j = blockIdx.x * 256 + t;
  if (j < 1664) {
    const float* W; const float* b; int col; int stride;
    if (j < 512)       { W = wq;    b = bq;    col = j;        stride = 512; }
    else if (j < 1024) { W = wk;    b = bk;    col = j - 512;  stride = 512; }
    else if (j < 1536) { W = wv;    b = bv;    col = j - 1024; stride = 512; }
    else               { W = wskip; b = bskip; col = j - 1536; stride = 128; }
    float a = b[col];
    for (int i = 0; i < H_DIM; ++i) a += es[i] * W[(D_DIM + i) * stride + col];
    cvec1[j] = a;
  } else if (j < 1664 + 384) {
    int j2 = j - 1664;
    int src = (j2 < 128) ? j2 : j2 + 128;   // i | g | o
    cvec2[j2] = bih[src] + bhh[src];
  }
}

// ---------------------------------------------------------------------------
// Fused weight split: all B panels -> one [3072][128] hi/lo bf16 buffer,
// granule-swizzled. wih columns permuted to (i,g,o).
// ---------------------------------------------------------------------------
__global__ __launch_bounds__(256) void k_split_all(
    const float* __restrict__ wq, const float* __restrict__ wk,
    const float* __restrict__ wv, const float* __restrict__ wskip,
    const float* __restrict__ g0w, const float* __restrict__ g1w,
    const float* __restrict__ wih,
    u16* __restrict__ hi, u16* __restrict__ lo)
{
  int idx = blockIdx.x * 256 + threadIdx.x;  // n*16 + g
  if (idx >= BCOL_TOT * 16) return;
  int n = idx >> 4, g = idx & 15;
  const float* W; int col, stride;
  if (n < 512)        { W = wq;    col = n;        stride = 512; }
  else if (n < 1024)  { W = wk;    col = n - 512;  stride = 512; }
  else if (n < 1536)  { W = wv;    col = n - 1024; stride = 512; }
  else if (n < 1664)  { W = wskip; col = n - 1536; stride = 128; }
  else if (n < 2176)  { W = g0w;   col = n - 1664; stride = 512; }
  else if (n < 2688)  { W = g1w;   col = n - 2176; stride = 512; }
  else { int c = n - 2688; W = wih; col = (c < 128) ? c : c + 128; stride = 512; }
  int gp = g ^ (n & 7);
  size_t dst = (size_t)n * 128 + gp * 8;
#pragma unroll
  for (int j = 0; j < 8; ++j) {
    u16 h, l;
    split_bf16(W[(size_t)(g * 8 + j) * stride + col], h, l);
    hi[dst + j] = h; lo[dst + j] = l;
  }
}

// ---------------------------------------------------------------------------
__global__ __launch_bounds__(256) void k_split_a(
    const float* __restrict__ A, const int* __restrict__ ids,
    u16* __restrict__ hi, u16* __restrict__ lo, int M, int Mpad)
{
  int idx = blockIdx.x * 256 + threadIdx.x;   // row*16 + g
  if (idx >= Mpad * 16) return;
  int row = idx >> 4, g = idx & 15;
  int gp = g ^ (row & 7);
  size_t dst = (size_t)row * 128 + gp * 8;
  if (row < M) {
    int ar = ids ? ids[row] : row;
    const float* srcp = A + (size_t)ar * 128 + g * 8;
#pragma unroll
    for (int j = 0; j < 8; ++j) {
      u16 h, l;
      split_bf16(srcp[j], h, l);
      hi[dst + j] = h; lo[dst + j] = l;
    }
  } else {
#pragma unroll
    for (int j = 0; j < 8; ++j) { hi[dst + j] = 0; lo[dst + j] = 0; }
  }
}

// ---------------------------------------------------------------------------
// Split-bf16 MFMA GEMM, BK=64 two-phase, 64KB LDS, register prefetch.
// Epilogue: bf16 panel for cols [0,bf_cols); fp32 out for cols >= f32_lo at
// stride ld_f32; optional fused per-head a_s/a_d reduce (head = bn>>7).
// ---------------------------------------------------------------------------
__global__ __launch_bounds__(256, 2) void mfma_gemm(
    const u16* __restrict__ Ahi, const u16* __restrict__ Alo,
    const u16* __restrict__ Bhi, const u16* __restrict__ Blo,
    const float* __restrict__ cvec,
    u16* __restrict__ bf_out, int bf_cols,
    float* __restrict__ f32_out, int f32_lo, int ld_f32,
    const float* __restrict__ asw, const float* __restrict__ adw,
    float* __restrict__ a_s, float* __restrict__ a_d,
    int M)
{
  __shared__ u16 lds[32768];   // 64 KB
  u16* As_hi = lds;
  u16* As_lo = lds + 8192;
  u16* Bs_hi = lds + 16384;
  u16* Bs_lo = lds + 24576;

  const int t = threadIdx.x;
  const int bm = blockIdx.y * 128;
  const int bn = blockIdx.x * 128;
  const int lane = t & 63;
  const int wid = t >> 6;
  const int wr = wid >> 1, wc = wid & 1;
  const int abase = wr * 64 + (lane & 15);
  const int bbase = wc * 64 + (lane & 15);

  int srow[4], sg[4];
#pragma unroll
  for (int i = 0; i < 4; ++i) {
    int idx = i * 256 + t;
    srow[i] = idx >> 3;
    sg[i] = idx & 7;
  }

  ushort8v ra_h[4], ra_l[4], rb_h[4], rb_l[4];

#pragma unroll
  for (int i = 0; i < 4; ++i) {
    size_t ga = (size_t)(bm + srow[i]) * 128 + sg[i] * 8;
    size_t gb = (size_t)(bn + srow[i]) * 128 + sg[i] * 8;
    ra_h[i] = *(const ushort8v*)&Ahi[ga];
    ra_l[i] = *(const ushort8v*)&Alo[ga];
    rb_h[i] = *(const ushort8v*)&Bhi[gb];
    rb_l[i] = *(const ushort8v*)&Blo[gb];
  }
#pragma unroll
  for (int i = 0; i < 4; ++i) {
    int lo_ = srow[i] * 64 + sg[i] * 8;
    *(ushort8v*)&As_hi[lo_] = ra_h[i];
    *(ushort8v*)&As_lo[lo_] = ra_l[i];
    *(ushort8v*)&Bs_hi[lo_] = rb_h[i];
    *(ushort8v*)&Bs_lo[lo_] = rb_l[i];
  }
  __syncthreads();

#pragma unroll
  for (int i = 0; i < 4; ++i) {
    size_t ga = (size_t)(bm + srow[i]) * 128 + 64 + sg[i] * 8;
    size_t gb = (size_t)(bn + srow[i]) * 128 + 64 + sg[i] * 8;
    ra_h[i] = *(const ushort8v*)&Ahi[ga];
    ra_l[i] = *(const ushort8v*)&Alo[ga];
    rb_h[i] = *(const ushort8v*)&Bhi[gb];
    rb_l[i] = *(const ushort8v*)&Blo[gb];
  }

  f32x4 acc[4][4];
  const f32x4 zero = {0.f, 0.f, 0.f, 0.f};
#pragma unroll
  for (int i = 0; i < 4; ++i)
#pragma unroll
    for (int j = 0; j < 4; ++j) acc[i][j] = zero;

#pragma unroll
  for (int ks = 0; ks < 2; ++ks) {
    const int gl = (((ks & 1) << 2) + (lane >> 4)) ^ (lane & 7);
    bf16x8 ah[4], al[4], bh[4], bl[4];
#pragma unroll
    for (int i = 0; i < 4; ++i) {
      int ra = (abase + i * 16) * 64 + gl * 8;
      ah[i] = *(const bf16x8*)&As_hi[ra];
      al[i] = *(const bf16x8*)&As_lo[ra];
      int rb = (bbase + i * 16) * 64 + gl * 8;
      bh[i] = *(const bf16x8*)&Bs_hi[rb];
      bl[i] = *(const bf16x8*)&Bs_lo[rb];
    }
#pragma unroll
    for (int i = 0; i < 4; ++i)
#pragma unroll
      for (int j = 0; j < 4; ++j) {
        acc[i][j] = __builtin_amdgcn_mfma_f32_16x16x32_bf16(ah[i], bh[j], acc[i][j], 0, 0, 0);
        acc[i][j] = __builtin_amdgcn_mfma_f32_16x16x32_bf16(ah[i], bl[j], acc[i][j], 0, 0, 0);
        acc[i][j] = __builtin_amdgcn_mfma_f32_16x16x32_bf16(al[i], bh[j], acc[i][j], 0, 0, 0);
      }
  }
  __syncthreads();

#pragma unroll
  for (int i = 0; i < 4; ++i) {
    int lo_ = srow[i] * 64 + sg[i] * 8;
    *(ushort8v*)&As_hi[lo_] = ra_h[i];
    *(ushort8v*)&As_lo[lo_] = ra_l[i];
    *(ushort8v*)&Bs_hi[lo_] = rb_h[i];
    *(ushort8v*)&Bs_lo[lo_] = rb_l[i];
  }
  __syncthreads();

#pragma unroll
  for (int ks = 2; ks < 4; ++ks) {
    const int gl = (((ks & 1) << 2) + (lane >> 4)) ^ (lane & 7);
    bf16x8 ah[4], al[4], bh[4], bl[4];
#pragma unroll
    for (int i = 0; i < 4; ++i) {
      int ra = (abase + i * 16) * 64 + gl * 8;
      ah[i] = *(const bf16x8*)&As_hi[ra];
      al[i] = *(const bf16x8*)&As_lo[ra];
      int rb = (bbase + i * 16) * 64 + gl * 8;
      bh[i] = *(const bf16x8*)&Bs_hi[rb];
      bl[i] = *(const bf16x8*)&Bs_lo[rb];
    }
#pragma unroll
    for (int i = 0; i < 4; ++i)
#pragma unroll
      for (int j = 0; j < 4; ++j) {
        acc[i][j] = __builtin_amdgcn_mfma_f32_16x16x32_bf16(ah[i], bh[j], acc[i][j], 0, 0, 0);
        acc[i][j] = __builtin_amdgcn_mfma_f32_16x16x32_bf16(ah[i], bl[j], acc[i][j], 0, 0, 0);
        acc[i][j] = __builtin_amdgcn_mfma_f32_16x16x32_bf16(al[i], bh[j], acc[i][j], 0, 0, 0);
      }
  }

  const int rq = (lane >> 4) << 2;
  const int cq = lane & 15;
  const int head = bn >> 7;

  float ws_[4], wd_[4];
  float* redS = (float*)lds;          // [128]
  float* redD = ((float*)lds) + 128;  // [128]
  if (asw) {
#pragma unroll
    for (int j = 0; j < 4; ++j) {
      int cc = (wc * 64 + j * 16 + cq) & 127;
      ws_[j] = asw[head * 128 + cc];
      wd_[j] = adw[head * 128 + cc];
    }
    __syncthreads();                  // all LDS compute reads done
    if (t < 128) { redS[t] = 0.f; }
    else if (t < 256) { redD[t - 128] = 0.f; }
    __syncthreads();
  }

#pragma unroll
  for (int i = 0; i < 4; ++i) {
#pragma unroll
    for (int r = 0; r < 4; ++r) {
      int rowl = wr * 64 + i * 16 + rq + r;
      int row = bm + rowl;
      bool rok = row < M;
      float ps = 0.f, pd = 0.f;
#pragma unroll
      for (int j = 0; j < 4; ++j) {
        int col = bn + wc * 64 + j * 16 + cq;
        float a = acc[i][j][r];
        if (rok) {
          float val = a + (cvec ? cvec[col] : 0.f);
          if (bf_out && col < bf_cols)
            bf_out[(size_t)row * bf_cols + col] =
                __builtin_bit_cast(u16, (__bf16)val);
          if (f32_out && col >= f32_lo)
            f32_out[(size_t)row * ld_f32 + (col - f32_lo)] = val;
        }
        if (asw) { ps += a * ws_[j]; pd += a * wd_[j]; }
      }
      if (asw && rok) {
        atomicAdd(&redS[rowl], ps);
        atomicAdd(&redD[rowl], pd);
      }
    }
  }
  if (asw) {
    __syncthreads();
    if (t < 128) {
      int row = bm + t;
      if (row < M) {
        a_s[row * 4 + head] = redS[t];
        a_d[row * 4 + head] = redD[t];
      }
    }
  }
}

// ---------------------------------------------------------------------------
__global__ __launch_bounds__(256) void k_zero(int* __restrict__ p, int n) {
  int i = blockIdx.x * 256 + threadIdx.x;
  if (i < n) p[i] = 0;
}
__global__ __launch_bounds__(256) void k_count(
    const int* __restrict__ dst, int* __restrict__ counts, int E) {
  int e = blockIdx.x * 256 + threadIdx.x;
  if (e < E) atomicAdd(&counts[dst[e]], 1);
}
__global__ __launch_bounds__(1024) void k_scan(
    const int* __restrict__ counts, int* __restrict__ offs,
    int* __restrict__ cursor, int N)
{
  __shared__ int wsum[16];
  const int t = threadIdx.x;
  const int lane = t & 63;
  const int wid = t >> 6;
  int running = 0;
  for (int base = 0; base < N; base += 1024) {
    int v = (base + t < N) ? counts[base + t] : 0;
    int incl = v;
#pragma unroll
    for (int s = 1; s < 64; s <<= 1) {
      int u = __shfl_up(incl, s);
      if (lane >= s) incl += u;
    }
    if (lane == 63) wsum[wid] = incl;
    __syncthreads();
    if (wid == 0) {
      int w = (lane < 16) ? wsum[lane] : 0;
#pragma unroll
      for (int s = 1; s < 16; s <<= 1) {
        int u = __shfl_up(w, s);
        if (lane >= s) w += u;
      }
      if (lane < 16) wsum[lane] = w;
    }
    __syncthreads();
    int wpre = (wid > 0) ? wsum[wid - 1] : 0;
    int tot = wsum[15];
    int inclg = incl + wpre;
    if (base + t < N) {
      offs[base + t + 1] = running + inclg;
      cursor[base + t] = running + inclg - v;
    }
    running += tot;
    __syncthreads();
  }
  if (t == 0) offs[0] = 0;
}
__global__ __launch_bounds__(256) void k_fill(
    const int* __restrict__ src, const int* __restrict__ dst,
    int* __restrict__ cursor, int* __restrict__ csr_src, int E) {
  int e = blockIdx.x * 256 + threadIdx.x;
  if (e < E) {
    int slot = atomicAdd(&cursor[dst[e]], 1);
    csr_src[slot] = src[e];
  }
}

// ---------------------------------------------------------------------------
// TransformerConv aggregation, ONLINE softmax, 4-edge unrolled.
// q/K/V from bf16 panel QKVp[N][1536] (q|k|v); skip from fp32 skipbuf[N][128].
// ---------------------------------------------------------------------------
__global__ __launch_bounds__(256) void k_tconv(
    const u16* __restrict__ QKVp, const float* __restrict__ skipbuf,
    const int* __restrict__ offs, const int* __restrict__ csr_src,
    u16* __restrict__ Xhi, u16* __restrict__ Xlo, int N)
{
  const int wid = threadIdx.x >> 6;
  const int lane = threadIdx.x & 63;
  const int node = blockIdx.x * 4 + wid;
  if (node >= N) {
    if (lane < 16) {
      size_t dst = (size_t)node * 128 + (size_t)((lane ^ (node & 7)) * 8);
#pragma unroll
      for (int j = 0; j < 8; ++j) { Xhi[dst + j] = 0; Xlo[dst + j] = 0; }
    }
    return;
  }
  float q[8];
  {
    bf16x8 qv = *(const bf16x8*)(QKVp + (size_t)node * 1536 + lane * 8);
#pragma unroll
    for (int j = 0; j < 8; ++j) q[j] = (float)qv[j];
  }
  const int beg = offs[node], end = offs[node + 1];
  float mx = -1e30f;
  float ssum = 0.f;
  float acc[8] = {0.f,0.f,0.f,0.f,0.f,0.f,0.f,0.f};

  int e = beg;
  for (; e + 4 <= end; e += 4) {
    int s0 = csr_src[e];
    int s1 = csr_src[e + 1];
    int s2 = csr_src[e + 2];
    int s3 = csr_src[e + 3];
    const u16* r0 = QKVp + (size_t)s0 * 1536 + 512 + lane * 8;
    const u16* r1 = QKVp + (size_t)s1 * 1536 + 512 + lane * 8;
    const u16* r2 = QKVp + (size_t)s2 * 1536 + 512 + lane * 8;
    const u16* r3 = QKVp + (size_t)s3 * 1536 + 512 + lane * 8;
    bf16x8 k0 = *(const bf16x8*)(r0);
    bf16x8 k1 = *(const bf16x8*)(r1);
    bf16x8 k2 = *(const bf16x8*)(r2);
    bf16x8 k3 = *(const bf16x8*)(r3);
    bf16x8 v0 = *(const bf16x8*)(r0 + 512);
    bf16x8 v1 = *(const bf16x8*)(r1 + 512);
    bf16x8 v2 = *(const bf16x8*)(r2 + 512);
    bf16x8 v3 = *(const bf16x8*)(r3 + 512);
    float p0 = 0.f, p1 = 0.f, p2 = 0.f, p3 = 0.f;
#pragma unroll
    for (int j = 0; j < 8; ++j) {
      p0 += q[j] * (float)k0[j];
      p1 += q[j] * (float)k1[j];
      p2 += q[j] * (float)k2[j];
      p3 += q[j] * (float)k3[j];
    }
    p0 = grp16_sum(p0) * SQRT_H_INV;
    p1 = grp16_sum(p1) * SQRT_H_INV;
    p2 = grp16_sum(p2) * SQRT_H_INV;
    p3 = grp16_sum(p3) * SQRT_H_INV;
    float nm = fmaxf(fmaxf(fmaxf(p0, p1), fmaxf(p2, p3)), mx);
    float sc = expf(mx - nm);
    float w0 = expf(p0 - nm);
    float w1 = expf(p1 - nm);
    float w2 = expf(p2 - nm);
    float w3 = expf(p3 - nm);
    ssum = ssum * sc + (w0 + w1) + (w2 + w3);
#pragma unroll
    for (int j = 0; j < 8; ++j)
      acc[j] = acc[j] * sc + (w0 * (float)v0[j] + w1 * (float)v1[j])
                           + (w2 * (float)v2[j] + w3 * (float)v3[j]);
    mx = nm;
  }
  for (; e < end; ++e) {
    int s0 = csr_src[e];
    const u16* r0 = QKVp + (size_t)s0 * 1536 + 512 + lane * 8;
    bf16x8 ka = *(const bf16x8*)(r0);
    bf16x8 va = *(const bf16x8*)(r0 + 512);
    float p0 = 0.f;
#pragma unroll
    for (int j = 0; j < 8; ++j) p0 += q[j] * (float)ka[j];
    p0 = grp16_sum(p0) * SQRT_H_INV;
    float nm = fmaxf(mx, p0);
    float sc = expf(mx - nm);
    float w0 = expf(p0 - nm);
    ssum = ssum * sc + w0;
#pragma unroll
    for (int j = 0; j < 8; ++j)
      acc[j] = acc[j] * sc + w0 * (float)va[j];
    mx = nm;
  }

  float inv = 1.f / (ssum + 1e-16f);
#pragma unroll
  for (int j = 0; j < 8; ++j) acc[j] *= inv;
#pragma unroll
  for (int j = 0; j < 8; ++j) {
    acc[j] += __shfl_xor(acc[j], 16);
    acc[j] += __shfl_xor(acc[j], 32);
  }
  if (lane < 16) {
    const float* sk = skipbuf + (size_t)node * 128 + lane * 8;
    size_t dst = (size_t)node * 128 + (size_t)((lane ^ (node & 7)) * 8);
#pragma unroll
    for (int j = 0; j < 8; ++j) {
      float x = 0.25f * acc[j] + sk[j];
      u16 h, l;
      split_bf16(x, h, l);
      Xhi[dst + j] = h; Xlo[dst + j] = l;
    }
  }
}

// ---------------------------------------------------------------------------
// GAT aggregation, ONLINE softmax, 4-edge unrolled; self + neighbors from
// bf16 panel xhb[N][512]; writes split hi/lo bf16 for next GEMM.
// ---------------------------------------------------------------------------
__global__ __launch_bounds__(256) void k_gat_agg(
    const u16* __restrict__ xhb,
    const float* __restrict__ a_s, const float* __restrict__ a_d,
    const int* __restrict__ offs, const int* __restrict__ csr_src,
    const float* __restrict__ bias,
    u16* __restrict__ Xhi, u16* __restrict__ Xlo, int N)
{
  const int wid = threadIdx.x >> 6;
  const int lane = threadIdx.x & 63;
  const int node = blockIdx.x * 4 + wid;
  if (node >= N) {
    if (lane < 16) {
      size_t dst = (size_t)node * 128 + (size_t)((lane ^ (node & 7)) * 8);
#pragma unroll
      for (int j = 0; j < 8; ++j) { Xhi[dst + j] = 0; Xlo[dst + j] = 0; }
    }
    return;
  }
  const int head = lane >> 4;
  const float adn = a_d[node * 4 + head];
  const float asn = a_s[node * 4 + head];
  float lself = asn + adn;
  lself = lself >= 0.f ? lself : 0.2f * lself;

  float mx = lself;
  float ssum = 1.f;
  float acc[8];
  {
    bf16x8 xs = *(const bf16x8*)(xhb + (size_t)node * 512 + lane * 8);
#pragma unroll
    for (int j = 0; j < 8; ++j) acc[j] = (float)xs[j];
  }

  const int beg = offs[node], end = offs[node + 1];
  int e = beg;
  for (; e + 4 <= end; e += 4) {
    int s0 = csr_src[e];
    int s1 = csr_src[e + 1];
    int s2 = csr_src[e + 2];
    int s3 = csr_src[e + 3];
    float l0 = a_s[s0 * 4 + head];
    float l1 = a_s[s1 * 4 + head];
    float l2 = a_s[s2 * 4 + head];
    float l3 = a_s[s3 * 4 + head];
    const u16* r0 = xhb + (size_t)s0 * 512 + lane * 8;
    const u16* r1 = xhb + (size_t)s1 * 512 + lane * 8;
    const u16* r2 = xhb + (size_t)s2 * 512 + lane * 8;
    const u16* r3 = xhb + (size_t)s3 * 512 + lane * 8;
    bf16x8 xa = *(const bf16x8*)(r0);
    bf16x8 xb = *(const bf16x8*)(r1);
    bf16x8 xc = *(const bf16x8*)(r2);
    bf16x8 xd = *(const bf16x8*)(r3);
    l0 += adn; l1 += adn; l2 += adn; l3 += adn;
    l0 = l0 >= 0.f ? l0 : 0.2f * l0;
    l1 = l1 >= 0.f ? l1 : 0.2f * l1;
    l2 = l2 >= 0.f ? l2 : 0.2f * l2;
    l3 = l3 >= 0.f ? l3 : 0.2f * l3;
    float nm = fmaxf(fmaxf(fmaxf(l0, l1), fmaxf(l2, l3)), mx);
    float sc = expf(mx - nm);
    float w0 = expf(l0 - nm);
    float w1 = expf(l1 - nm);
    float w2 = expf(l2 - nm);
    float w3 = expf(l3 - nm);
    ssum = ssum * sc + (w0 + w1) + (w2 + w3);
#pragma unroll
    for (int j = 0; j < 8; ++j)
      acc[j] = acc[j] * sc + (w0 * (float)xa[j] + w1 * (float)xb[j])
                           + (w2 * (float)xc[j] + w3 * (float)xd[j]);
    mx = nm;
  }
  for (; e < end; ++e) {
    int s0 = csr_src[e];
    float l0 = a_s[s0 * 4 + head] + adn;
    l0 = l0 >= 0.f ? l0 : 0.2f * l0;
    const u16* r0 = xhb + (size_t)s0 * 512 + lane * 8;
    bf16x8 xa = *(const bf16x8*)(r0);
    float nm = fmaxf(mx, l0);
    float sc = expf(mx - nm);
    float w0 = expf(l0 - nm);
    ssum = ssum * sc + w0;
#pragma unroll
    for (int j = 0; j < 8; ++j)
      acc[j] = acc[j] * sc + w0 * (float)xa[j];
    mx = nm;
  }

  float inv = 1.f / (ssum + 1e-16f);
#pragma unroll
  for (int j = 0; j < 8; ++j) acc[j] *= inv;
#pragma unroll
  for (int j = 0; j < 8; ++j) {
    acc[j] += __shfl_xor(acc[j], 16);
    acc[j] += __shfl_xor(acc[j], 32);
  }
  if (lane < 16) {
    const float* b = bias + lane * 8;
    size_t dst = (size_t)node * 128 + (size_t)((lane ^ (node & 7)) * 8);
#pragma unroll
    for (int j = 0; j < 8; ++j) {
      float x = fmaxf(0.25f * acc[j] + b[j], 0.f);
      u16 h, l;
      split_bf16(x, h, l);
      Xhi[dst + j] = h; Xlo[dst + j] = l;
    }
  }
}

// ---------------------------------------------------------------------------
// LSTM epilogue; gates[N][384] in (i,g,o) order. h0=c0=0.
// ---------------------------------------------------------------------------
__global__ __launch_bounds__(256) void k_lstm(
    const float* __restrict__ gates, float* __restrict__ out, int N)
{
  int idx = blockIdx.x * 256 + threadIdx.x;
  if (idx >= N * 128) return;
  int n = idx >> 7, c = idx & 127;
  const float* g = gates + (size_t)n * 384;
  float gi = g[c], gg = g[128 + c], go = g[256 + c];
  float cv = (1.f / (1.f + expf(-gi))) * tanhf(gg);
  float hv = (1.f / (1.f + expf(-go))) * tanhf(cv);
  out[idx] = hv;
  out[(size_t)N * 128 + idx] = cv;
}

// ---------------------------------------------------------------------------
extern "C" void kernel_launch(void* const* d_in, const int* in_sizes, int n_in,
                              void* d_out, int out_size, void* d_ws, size_t ws_size,
                              hipStream_t stream) {
  const int*   node_ids = (const int*)d_in[0];
  const int*   etid     = (const int*)d_in[1];
  const int*   src      = (const int*)d_in[2];
  const int*   dst      = (const int*)d_in[3];
  const float* ef       = (const float*)d_in[4];
  const float* inten    = (const float*)d_in[5];
  const float* nemb     = (const float*)d_in[6];
  const float* ett      = (const float*)d_in[7];
  const float* ev_w1 = (const float*)d_in[8],  *ev_b1 = (const float*)d_in[9];
  const float* ev_g1 = (const float*)d_in[10], *ev_bt1 = (const float*)d_in[11];
  const float* ev_w2 = (const float*)d_in[12], *ev_b2 = (const float*)d_in[13];
  const float* ev_g2 = (const float*)d_in[14], *ev_bt2 = (const float*)d_in[15];
  const float* wq = (const float*)d_in[16], *bq = (const float*)d_in[17];
  const float* wk = (const float*)d_in[18], *bk = (const float*)d_in[19];
  const float* wv = (const float*)d_in[20], *bv = (const float*)d_in[21];
  const float* wskip = (const float*)d_in[22], *bskip = (const float*)d_in[23];
  const float* g0_w = (const float*)d_in[24], *g0_as = (const float*)d_in[25];
  const float* g0_ad = (const float*)d_in[26], *g0_b = (const float*)d_in[27];
  const float* g1_w = (const float*)d_in[28], *g1_as = (const float*)d_in[29];
  const float* g1_ad = (const float*)d_in[30], *g1_b = (const float*)d_in[31];
  const float* wih = (const float*)d_in[32];
  const float* bih = (const float*)d_in[34], *bhh = (const float*)d_in[35];

  const int N = in_sizes[0];
  const int K = in_sizes[1];
  const int E = in_sizes[2];
  const int EV = in_sizes[4];

  const int gridMy = (N + 127) / 128;
  const int Npad = gridMy * 128;

  float* ws = (float*)d_ws;
  size_t o = 0;
  float* e_vec = ws + o; o += 128;
  float* cvec1 = ws + o; o += 1664;
  float* cvec2 = ws + o; o += 384;
  u16* Ballhi = (u16*)(ws + o); o += (size_t)BCOL_TOT * 64;
  u16* Balllo = (u16*)(ws + o); o += (size_t)BCOL_TOT * 64;
  u16* Ahi  = (u16*)(ws + o); o += (size_t)Npad * 64;
  u16* Alo  = (u16*)(ws + o); o += (size_t)Npad * 64;
  u16* XShi = (u16*)(ws + o); o += (size_t)Npad * 64;
  u16* XSlo = (u16*)(ws + o); o += (size_t)Npad * 64;
  u16* QKVp = (u16*)(ws + o); o += (size_t)Npad * 768;   // [N][1536] u16
  float* skipbuf = ws + o; o += (size_t)Npad * 128;
  u16* xhb  = (u16*)(ws + o); o += (size_t)Npad * 256;   // [N][512] u16
  float* gates = ws + o; o += (size_t)Npad * 384;
  float* a_s   = ws + o; o += (size_t)N * 4;
  float* a_d   = ws + o; o += (size_t)N * 4;
  int* counts  = (int*)(ws + o); o += N;
  int* offs    = (int*)(ws + o); o += (size_t)N + 1;
  int* cursor  = (int*)(ws + o); o += N;
  int* csr_src = (int*)(ws + o); o += E;

  float* out = (float*)d_out;
  const int nodeBlocksPad = Npad / 4;

  k_event<<<1, 128, 0, stream>>>(ef, EV, ev_w1, ev_b1, ev_g1, ev_bt1,
                                 ev_w2, ev_b2, ev_g2, ev_bt2,
                                 ett, etid, inten, K, e_vec);
  k_cvec_all<<<8, 256, 0, stream>>>(e_vec, wq, bq, wk, bk, wv, bv,
                                    wskip, bskip, bih, bhh, cvec1, cvec2);
  k_split_all<<<(BCOL_TOT * 16) / 256, 256, 0, stream>>>(
      wq, wk, wv, wskip, g0_w, g1_w, wih, Ballhi, Balllo);
  k_split_a<<<(Npad * 16 + 255) / 256, 256, 0, stream>>>(nemb, node_ids, Ahi, Alo, N, Npad);

  k_zero<<<(N + 255) / 256, 256, 0, stream>>>(counts, N);
  k_count<<<(E + 255) / 256, 256, 0, stream>>>(dst, counts, E);
  k_scan<<<1, 1024, 0, stream>>>(counts, offs, cursor, N);
  k_fill<<<(E + 255) / 256, 256, 0, stream>>>(src, dst, cursor, csr_src, E);

  // QKV: bf16 q|k|v -> QKVp; fp32 skip -> skipbuf
  mfma_gemm<<<dim3(13, gridMy), 256, 0, stream>>>(
      Ahi, Alo, Ballhi + (size_t)BCOL_QKV * 128, Balllo + (size_t)BCOL_QKV * 128,
      cvec1, QKVp, 1536, skipbuf, 1536, 128,
      nullptr, nullptr, nullptr, nullptr, N);

  k_tconv<<<nodeBlocksPad, 256, 0, stream>>>(QKVp, skipbuf, offs, csr_src,
                                             XShi, XSlo, N);

  // GAT layer 1: bf16 xhb + fused a_s/a_d
  mfma_gemm<<<dim3(4, gridMy), 256, 0, stream>>>(
      XShi, XSlo, Ballhi + (size_t)BCOL_G0 * 128, Balllo + (size_t)BCOL_G0 * 128,
      nullptr, xhb, 512, nullptr, 0, 0,
      g0_as, g0_ad, a_s, a_d, N);
  k_gat_agg<<<nodeBlocksPad, 256, 0, stream>>>(xhb, a_s, a_d, offs, csr_src,
                                               g0_b, XShi, XSlo, N);

  // GAT layer 2
  mfma_gemm<<<dim3(4, gridMy), 256, 0, stream>>>(
      XShi, XSlo, Ballhi + (size_t)BCOL_G1 * 128, Balllo + (size_t)BCOL_G1 * 128,
      nullptr, xhb, 512, nullptr, 0, 0,
      g1_as, g1_ad, a_s, a_d, N);
  k_gat_agg<<<nodeBlocksPad, 256, 0, stream>>>(xhb, a_s, a_d, offs, csr_src,
                                               g1_b, XShi, XSlo, N);

  // LSTM: fp32 gates (i,g,o) 384 wide
  mfma_gemm<<<dim3(3, gridMy), 256, 0, stream>>>(
      XShi, XSlo, Ballhi + (size_t)BCOL_W * 128, Balllo + (size_t)BCOL_W * 128,
      cvec2, nullptr, 0, gates, 0, 384,
      nullptr, nullptr, nullptr, nullptr, N);
  k_lstm<<<((N * 128) + 255) / 256, 256, 0, stream>>>(gates, out, N);
}